// Round 1
// baseline (118.505 us; speedup 1.0000x reference)
//
#include <hip/hip_runtime.h>
#include <math.h>

#define BB 4
#define CC 248
#define TT 500
#define DD 64

__device__ __forceinline__ float waveReduceSum(float v) {
    #pragma unroll
    for (int off = 32; off > 0; off >>= 1) v += __shfl_xor(v, off, 64);
    return v;
}

__global__ __launch_bounds__(256) void csa_kernel(
    const float* __restrict__ x,
    const float* __restrict__ wq, const float* __restrict__ bq,
    const float* __restrict__ wk, const float* __restrict__ bk,
    const float* __restrict__ wv, const float* __restrict__ bv,
    float* __restrict__ out, float* __restrict__ wts)
{
    const int bt = blockIdx.x;          // 0 .. B*T-1
    const int b  = bt / TT;
    const int t  = bt % TT;
    const int tid  = threadIdx.x;
    const int wave = tid >> 6;
    const int lane = tid & 63;

    __shared__ __align__(16) float xs[CC];
    __shared__ float sred[8];
    __shared__ float sA, sB2, sXmax, sXmin, sYbar;

    // ---- load x slice: x[b, c, t], c = tid ----
    if (tid < CC) xs[tid] = x[((size_t)b * CC + tid) * TT + t];

    // ---- wave 1 computes the two needed scalars: a = wq.wk/8, b2 = bq.wk/8 ----
    if (wave == 1) {
        float wkv = wk[lane];
        float pa = wq[lane] * wkv;
        float pb = bq[lane] * wkv;
        #pragma unroll
        for (int off = 32; off > 0; off >>= 1) {
            pa += __shfl_xor(pa, off, 64);
            pb += __shfl_xor(pb, off, 64);
        }
        if (lane == 0) { sA = pa * 0.125f; sB2 = pb * 0.125f; }
    }
    __syncthreads();

    // ---- block reduce xmax / xmin over the 248 values ----
    float vmax = -INFINITY, vmin = INFINITY;
    if (tid < CC) { vmax = xs[tid]; vmin = xs[tid]; }
    #pragma unroll
    for (int off = 32; off > 0; off >>= 1) {
        vmax = fmaxf(vmax, __shfl_xor(vmax, off, 64));
        vmin = fminf(vmin, __shfl_xor(vmin, off, 64));
    }
    if (lane == 0) { sred[wave] = vmax; sred[4 + wave] = vmin; }
    __syncthreads();
    if (tid == 0) {
        sXmax = fmaxf(fmaxf(sred[0], sred[1]), fmaxf(sred[2], sred[3]));
        sXmin = fminf(fminf(sred[4], sred[5]), fminf(sred[6], sred[7]));
    }
    __syncthreads();

    const float a    = sA;
    const float b2   = sB2;
    const float xmax = sXmax;
    const float xmin = sXmin;
    const float4* xs4 = reinterpret_cast<const float4*>(xs);

    // per-lane copy of xs chunk for this lane (reused every row)
    float4 xv = make_float4(0.f, 0.f, 0.f, 0.f);
    const bool active = (lane < CC / 4);        // lanes 0..61
    if (active) xv = xs4[lane];

    float ywave = 0.f;
    const size_t slice = (size_t)bt * CC * CC;

    for (int c = wave; c < CC; c += 4) {
        const float sc = fmaf(a, xs[c], b2);
        const float m  = (sc >= 0.f) ? sc * xmax : sc * xmin;

        float4 p = make_float4(0.f, 0.f, 0.f, 0.f);
        float sum = 0.f, xp = 0.f;
        if (active) {
            p.x = __expf(fmaf(sc, xv.x, -m));
            p.y = __expf(fmaf(sc, xv.y, -m));
            p.z = __expf(fmaf(sc, xv.z, -m));
            p.w = __expf(fmaf(sc, xv.w, -m));
            sum = (p.x + p.y) + (p.z + p.w);
            xp  = (p.x * xv.x + p.y * xv.y) + (p.z * xv.z + p.w * xv.w);
        }
        const float denom = waveReduceSum(sum);
        const float xps   = waveReduceSum(xp);
        const float inv   = 1.0f / denom;

        if (active) {
            float4 o;
            o.x = p.x * inv; o.y = p.y * inv; o.z = p.z * inv; o.w = p.w * inv;
            reinterpret_cast<float4*>(wts + slice + (size_t)c * CC)[lane] = o;
        }
        ywave += xps * inv;
    }

    if (lane == 0) sred[wave] = ywave;
    __syncthreads();
    if (tid == 0)
        sYbar = (sred[0] + sred[1] + sred[2] + sred[3]) * (1.0f / CC);
    __syncthreads();

    if (tid < DD)
        out[(size_t)bt * DD + tid] = fmaf(wv[tid], sYbar, bv[tid]);
}

extern "C" void kernel_launch(void* const* d_in, const int* in_sizes, int n_in,
                              void* d_out, int out_size, void* d_ws, size_t ws_size,
                              hipStream_t stream) {
    const float* x  = (const float*)d_in[0];
    const float* wq = (const float*)d_in[1];
    const float* bq = (const float*)d_in[2];
    const float* wk = (const float*)d_in[3];
    const float* bk = (const float*)d_in[4];
    const float* wv = (const float*)d_in[5];
    const float* bv = (const float*)d_in[6];

    float* out = (float*)d_out;                          // [B,T,D] = 128000 floats
    float* wts = (float*)d_out + (size_t)BB * TT * DD;   // [B,T,C,C]

    csa_kernel<<<dim3(BB * TT), dim3(256), 0, stream>>>(x, wq, bq, wk, bk, wv, bv, out, wts);
}

// Round 2
// 104.506 us; speedup vs baseline: 1.1340x; 1.1340x over previous
//
#include <hip/hip_runtime.h>
#include <math.h>

#define BB 4
#define CC 248
#define TT 500
#define DD 64

typedef float f32x4 __attribute__((ext_vector_type(4)));

__global__ __launch_bounds__(256) void csa_kernel(
    const float* __restrict__ x,
    const float* __restrict__ wq, const float* __restrict__ bq,
    const float* __restrict__ wk, const float* __restrict__ bk,
    const float* __restrict__ wv, const float* __restrict__ bv,
    float* __restrict__ out, float* __restrict__ wts)
{
    const int bt = blockIdx.x;          // 0 .. B*T-1
    const int b  = bt / TT;
    const int t  = bt % TT;
    const int tid  = threadIdx.x;
    const int wave = tid >> 6;
    const int lane = tid & 63;
    const int q    = lane & 31;         // index within half-wave
    const int h    = lane >> 5;         // which half-wave

    __shared__ __align__(16) float xs[CC];
    __shared__ float sred[8];
    __shared__ float sA, sB2, sXmax, sXmin, sYbar;

    // ---- load x slice: x[b, c, t] ----
    if (tid < CC) xs[tid] = x[((size_t)b * CC + tid) * TT + t];

    // ---- wave 1: a = wq.wk/8, b2 = bq.wk/8 (both pre-scaled by log2e later) ----
    if (wave == 1) {
        float wkv = wk[lane];
        float pa = wq[lane] * wkv;
        float pb = bq[lane] * wkv;
        #pragma unroll
        for (int off = 32; off > 0; off >>= 1) {
            pa += __shfl_xor(pa, off, 64);
            pb += __shfl_xor(pb, off, 64);
        }
        if (lane == 0) { sA = pa * 0.125f; sB2 = pb * 0.125f; }
    }
    __syncthreads();

    // ---- block reduce xmax / xmin ----
    float vmax = -INFINITY, vmin = INFINITY;
    if (tid < CC) { vmax = xs[tid]; vmin = vmax; }
    #pragma unroll
    for (int off = 32; off > 0; off >>= 1) {
        vmax = fmaxf(vmax, __shfl_xor(vmax, off, 64));
        vmin = fminf(vmin, __shfl_xor(vmin, off, 64));
    }
    if (lane == 0) { sred[wave] = vmax; sred[4 + wave] = vmin; }
    __syncthreads();
    if (tid == 0) {
        sXmax = fmaxf(fmaxf(sred[0], sred[1]), fmaxf(sred[2], sred[3]));
        sXmin = fminf(fminf(sred[4], sred[5]), fminf(sred[6], sred[7]));
    }
    __syncthreads();

    const float LOG2E = 1.4426950408889634f;
    const float a2   = sA  * LOG2E;      // scores pre-scaled: p = exp2(scl*x - ml)
    const float b22  = sB2 * LOG2E;
    const float xmax = sXmax;
    const float xmin = sXmin;

    const f32x4* xs4 = reinterpret_cast<const f32x4*>(xs);
    const bool act = (q < 31);           // 31 lanes × 8 floats = 248 cols
    f32x4 xlo = {0.f,0.f,0.f,0.f}, xhi = {0.f,0.f,0.f,0.f};
    if (act) { xlo = xs4[q]; xhi = xs4[31 + q]; }

    float ysum = 0.f;
    const size_t slice = (size_t)bt * (CC * CC);

    // 31 iterations; each wave retires TWO rows per iteration (one per half-wave)
    #pragma unroll 2
    for (int i = 0; i < 31; ++i) {
        const int r = 8 * i + 2 * wave + h;
        const float scl = fmaf(a2, xs[r], b22);
        const float ml  = (scl >= 0.f) ? scl * xmax : scl * xmin;

        f32x4 plo = {0.f,0.f,0.f,0.f}, phi = {0.f,0.f,0.f,0.f};
        float sum = 0.f, xp = 0.f;
        if (act) {
            plo.x = __builtin_amdgcn_exp2f(fmaf(scl, xlo.x, -ml));
            plo.y = __builtin_amdgcn_exp2f(fmaf(scl, xlo.y, -ml));
            plo.z = __builtin_amdgcn_exp2f(fmaf(scl, xlo.z, -ml));
            plo.w = __builtin_amdgcn_exp2f(fmaf(scl, xlo.w, -ml));
            phi.x = __builtin_amdgcn_exp2f(fmaf(scl, xhi.x, -ml));
            phi.y = __builtin_amdgcn_exp2f(fmaf(scl, xhi.y, -ml));
            phi.z = __builtin_amdgcn_exp2f(fmaf(scl, xhi.z, -ml));
            phi.w = __builtin_amdgcn_exp2f(fmaf(scl, xhi.w, -ml));
            sum = ((plo.x + plo.y) + (plo.z + plo.w)) + ((phi.x + phi.y) + (phi.z + phi.w));
            xp  = ((plo.x * xlo.x + plo.y * xlo.y) + (plo.z * xlo.z + plo.w * xlo.w))
                + ((phi.x * xhi.x + phi.y * xhi.y) + (phi.z * xhi.z + phi.w * xhi.w));
        }
        // 5-step reduce within each half-wave (xor<32 never crosses halves)
        #pragma unroll
        for (int off = 16; off > 0; off >>= 1) {
            sum += __shfl_xor(sum, off, 64);
            xp  += __shfl_xor(xp,  off, 64);
        }
        const float inv = __builtin_amdgcn_rcpf(sum);

        if (act) {
            f32x4 olo, ohi;
            olo.x = plo.x * inv; olo.y = plo.y * inv; olo.z = plo.z * inv; olo.w = plo.w * inv;
            ohi.x = phi.x * inv; ohi.y = phi.y * inv; ohi.z = phi.z * inv; ohi.w = phi.w * inv;
            f32x4* dst = reinterpret_cast<f32x4*>(wts + slice + (size_t)r * CC);
            dst[q]      = olo;   // cols 4q..4q+3      (contiguous 496 B per half)
            dst[31 + q] = ohi;   // cols 124+4q..      (contiguous 496 B per half)
        }
        ysum += xp * inv;
    }

    if (q == 0) sred[wave * 2 + h] = ysum;
    __syncthreads();
    if (tid == 0) {
        float s = 0.f;
        #pragma unroll
        for (int k = 0; k < 8; ++k) s += sred[k];
        sYbar = s * (1.0f / CC);
    }
    __syncthreads();

    if (tid < DD)
        out[(size_t)bt * DD + tid] = fmaf(wv[tid], sYbar, bv[tid]);
}

extern "C" void kernel_launch(void* const* d_in, const int* in_sizes, int n_in,
                              void* d_out, int out_size, void* d_ws, size_t ws_size,
                              hipStream_t stream) {
    const float* x  = (const float*)d_in[0];
    const float* wq = (const float*)d_in[1];
    const float* bq = (const float*)d_in[2];
    const float* wk = (const float*)d_in[3];
    const float* bk = (const float*)d_in[4];
    const float* wv = (const float*)d_in[5];
    const float* bv = (const float*)d_in[6];

    float* out = (float*)d_out;                          // [B,T,D]
    float* wts = (float*)d_out + (size_t)BB * TT * DD;   // [B,T,C,C]

    csa_kernel<<<dim3(BB * TT), dim3(256), 0, stream>>>(x, wq, bq, wk, bk, wv, bv, out, wts);
}